// Round 16
// baseline (326.327 us; speedup 1.0000x reference)
//
#include <hip/hip_runtime.h>
#include <math.h>

#define NSWEEP 6
#define NR (NSWEEP * 63)
#define EXIT_EPS 3e-6f

typedef __attribute__((ext_vector_type(2))) float f32x2;

// ---------------------------------------------------------------------------
// Kernel 1: partial max-pooled outer products. Grid = B*G blocks.
// ---------------------------------------------------------------------------
__global__ __launch_bounds__(256) void pool_kernel(const float* __restrict__ x,
                                                   float* __restrict__ part,
                                                   int G) {
  __shared__ float xs[4096];
  const int t = threadIdx.x;
  const int blk = blockIdx.x;
  const int b = blk / G, g = blk % G;
  const int npb = 4096 / G;
  const int ntile = npb >> 6;
  const int n0 = g * npb;
  const int i0 = (t >> 4) * 4;
  const int j0 = (t & 15) * 4;

  float mv[4][4];
#pragma unroll
  for (int a = 0; a < 4; ++a)
#pragma unroll
    for (int c = 0; c < 4; ++c) mv[a][c] = -INFINITY;

  const float4* src = reinterpret_cast<const float4*>(x + ((size_t)b * 4096 + n0) * 64);
  float4* xs4 = reinterpret_cast<float4*>(xs);

  for (int tile = 0; tile < ntile; ++tile) {
#pragma unroll
    for (int q = 0; q < 4; ++q) xs4[t + 256 * q] = src[(size_t)tile * 1024 + t + 256 * q];
    __syncthreads();
#pragma unroll 4
    for (int n = 0; n < 64; ++n) {
      const float4 vi = *reinterpret_cast<const float4*>(&xs[n * 64 + i0]);
      const float4 vj = *reinterpret_cast<const float4*>(&xs[n * 64 + j0]);
      const float fi[4] = {vi.x, vi.y, vi.z, vi.w};
      const float fj[4] = {vj.x, vj.y, vj.z, vj.w};
#pragma unroll
      for (int a = 0; a < 4; ++a)
#pragma unroll
        for (int c = 0; c < 4; ++c)
          mv[a][c] = fmaxf(mv[a][c], fi[a] * fj[c]);
    }
    __syncthreads();
  }

#pragma unroll
  for (int a = 0; a < 4; ++a)
#pragma unroll
    for (int c = 0; c < 4; ++c)
      xs[(i0 + a) * 64 + (j0 + c)] = mv[a][c];
  __syncthreads();

  float* dst = part + ((size_t)b * G + g) * 4096;
#pragma unroll
  for (int q = 0; q < 16; ++q) dst[t + 256 * q] = xs[t + 256 * q];
}

// ---------------------------------------------------------------------------
// Kernel 2: one-sided Jacobi, XOR schedule (pairs lane^m, m=1..63).
//   wave0 producer: packed f32x2, fused rotate+next-fetch, early bb prefetch,
//     convergence EARLY-EXIT at sweep boundaries (max|s| < EXIT_EPS).
//   wave1 consumer: V replay from LDS ring (R13-proven), honors ndone.
//   waves 2,3 park; all 4 waves run the proven R = W*V^T epilogue.
// ---------------------------------------------------------------------------
__device__ __forceinline__ float bperm(int byteaddr, float v) {
  return __int_as_float(__builtin_amdgcn_ds_bpermute(byteaddr, __float_as_int(v)));
}

__global__ __launch_bounds__(256, 1) void svd_kernel(const float* __restrict__ part,
                                                     float* __restrict__ out, int G) {
  __shared__ __align__(16) float Al[64 * 68];   // pooled A -> W -> R
  __shared__ __align__(16) float Vl[64 * 68];   // final V
  __shared__ float2 ring[64][64];
  __shared__ float red[4];
  __shared__ int pflag_s, cflag_s, ndone_s;

  const int b = blockIdx.x;
  const int t = threadIdx.x;
  const int wave = t >> 6, lane = t & 63;
  const int lane4 = lane << 2;

  if (t == 0) { pflag_s = 0; cflag_s = 0; ndone_s = NR; }

  // ---- prologue: fused max-reduce of partials into Al (all 256 threads) ----
  const float4* p4 = reinterpret_cast<const float4*>(part) + (size_t)b * G * 1024;
  float4 acc[4];
#pragma unroll
  for (int u = 0; u < 4; ++u) acc[u] = p4[t + 256 * u];
#pragma unroll 2
  for (int g = 1; g < G; ++g) {
#pragma unroll
    for (int u = 0; u < 4; ++u) {
      const float4 v = p4[(size_t)g * 1024 + t + 256 * u];
      acc[u].x = fmaxf(acc[u].x, v.x);
      acc[u].y = fmaxf(acc[u].y, v.y);
      acc[u].z = fmaxf(acc[u].z, v.z);
      acc[u].w = fmaxf(acc[u].w, v.w);
    }
  }
#pragma unroll
  for (int u = 0; u < 4; ++u) {
    const int idx = t + 256 * u;
    const int i = idx >> 4;
    const int j = (idx & 15) * 4;
    *reinterpret_cast<float4*>(&Al[i * 68 + j]) = acc[u];
  }
  __syncthreads();

  if (wave == 0) {
    // ========== producer: packed columns, early bb prefetch (R13) ==========
    f32x2 g2[32], ex2[32];
#pragma unroll
    for (int k = 0; k < 32; ++k)
      g2[k] = (f32x2){Al[(2 * k) * 68 + lane], Al[(2 * k + 1) * 68 + lane]};

    float a;
    {
      f32x2 n0 = (f32x2)(0.0f), n1 = (f32x2)(0.0f), n2 = (f32x2)(0.0f), n3 = (f32x2)(0.0f);
#pragma unroll
      for (int k = 0; k < 32; k += 4) {
        n0 = g2[k] * g2[k] + n0;
        n1 = g2[k + 1] * g2[k + 1] + n1;
        n2 = g2[k + 2] * g2[k + 2] + n2;
        n3 = g2[k + 3] * g2[k + 3] + n3;
      }
      const f32x2 nt = (n0 + n1) + (n2 + n3);
      a = nt.x + nt.y;
    }

    int m = 1;
    int addr = lane4 ^ (m << 2);
#pragma unroll
    for (int k = 0; k < 32; ++k) {
      ex2[k].x = bperm(addr, g2[k].x);
      ex2[k].y = bperm(addr, g2[k].y);
    }
    float bb = bperm(addr, a);

    float smax = 0.0f;
#pragma unroll 1
    for (int rg = 0; rg < NR; ++rg) {
      // dot product over cached partner column (8 packed chains)
      float d;
      {
        f32x2 d0 = (f32x2)(0.0f), d1 = (f32x2)(0.0f), d2 = (f32x2)(0.0f), d3 = (f32x2)(0.0f);
        f32x2 d4 = (f32x2)(0.0f), d5 = (f32x2)(0.0f), d6 = (f32x2)(0.0f), d7 = (f32x2)(0.0f);
#pragma unroll
        for (int k = 0; k < 32; k += 8) {
          d0 = g2[k] * ex2[k] + d0;
          d1 = g2[k + 1] * ex2[k + 1] + d1;
          d2 = g2[k + 2] * ex2[k + 2] + d2;
          d3 = g2[k + 3] * ex2[k + 3] + d3;
          d4 = g2[k + 4] * ex2[k + 4] + d4;
          d5 = g2[k + 5] * ex2[k + 5] + d5;
          d6 = g2[k + 6] * ex2[k + 6] + d6;
          d7 = g2[k + 7] * ex2[k + 7] + d7;
        }
        const f32x2 dt = ((d0 + d1) + (d2 + d3)) + ((d4 + d5) + (d6 + d7));
        d = dt.x + dt.y;
      }

      // angle: c identical on both pair lanes, s opposite sign
      const int partner = lane ^ m;
      const float u = (bb - a) * 0.5f;                  // exactly negated on partner
      const float sg = (u != 0.0f) ? copysignf(1.0f, u)
                                   : ((lane < partner) ? 1.0f : -1.0f);
      const float q = fmaf(u, u, d * d);
      float c, s;
      if (q > 0.0f) {
        const float rh = rsqrtf(q);                     // 1/h
        const float cc = fmaf(0.5f * fabsf(u), rh, 0.5f);  // c^2
        const float rc = rsqrtf(cc);
        c = cc * rc;
        s = d * sg * rh * 0.5f * rc;
      } else {
        c = 1.0f; s = 0.0f;
      }
      const float ns = -s;
      const float aupd = fmaf(c * c, a, fmaf(s * s, bb, -2.0f * (c * s) * d));
      smax = fmaxf(smax, fabsf(s));

      ring[rg & 63][lane] = make_float2(c, s);
      if ((rg & 15) == 15) {
        if (lane == 0)
          __hip_atomic_store(&pflag_s, rg + 1, __ATOMIC_RELEASE, __HIP_MEMORY_SCOPE_WORKGROUP);
        int cd = __hip_atomic_load(&cflag_s, __ATOMIC_ACQUIRE, __HIP_MEMORY_SCOPE_WORKGROUP);
        while (rg + 1 - cd > 40) {
          __builtin_amdgcn_s_sleep(1);
          cd = __hip_atomic_load(&cflag_s, __ATOMIC_ACQUIRE, __HIP_MEMORY_SCOPE_WORKGROUP);
        }
      }

      const int mn = (m == 63) ? 1 : m + 1;
      const int addrn = lane4 ^ (mn << 2);

      // EARLY bb prefetch (overlaps the rotate burst)
      float bbn = bperm(addrn, aupd);

      // fused: packed rotate own column, immediately issue next exchange
      const f32x2 c2 = {c, c}, ns2 = {ns, ns};
#pragma unroll
      for (int k = 0; k < 32; ++k) {
        g2[k] = ns2 * ex2[k] + c2 * g2[k];
        ex2[k].x = bperm(addrn, g2[k].x);
        ex2[k].y = bperm(addrn, g2[k].y);
      }

      if (mn == 1) {  // sweep boundary: convergence check + exact refresh
        float sm = smax;
#pragma unroll
        for (int off = 32; off; off >>= 1) sm = fmaxf(sm, __shfl_xor(sm, off, 64));
        if (sm < EXIT_EPS) {
          if (lane == 0)
            __hip_atomic_store(&ndone_s, rg + 1, __ATOMIC_RELEASE, __HIP_MEMORY_SCOPE_WORKGROUP);
          break;
        }
        smax = 0.0f;
        f32x2 n0 = (f32x2)(0.0f), n1 = (f32x2)(0.0f), n2 = (f32x2)(0.0f), n3 = (f32x2)(0.0f);
#pragma unroll
        for (int k = 0; k < 32; k += 4) {
          n0 = g2[k] * g2[k] + n0;
          n1 = g2[k + 1] * g2[k + 1] + n1;
          n2 = g2[k + 2] * g2[k + 2] + n2;
          n3 = g2[k + 3] * g2[k + 3] + n3;
        }
        const f32x2 nt = (n0 + n1) + (n2 + n3);
        a = nt.x + nt.y;
        bbn = bperm(addrn, a);
      } else {
        a = aupd;
      }
      bb = bbn;
      m = mn;
    }
    if (lane == 0)
      __hip_atomic_store(&pflag_s, NR, __ATOMIC_RELEASE, __HIP_MEMORY_SCOPE_WORKGROUP);

    // exact sigma; W = G * diag(sigma^{-1/2}) into Al
    float s2;
    {
      f32x2 n0 = (f32x2)(0.0f), n1 = (f32x2)(0.0f), n2 = (f32x2)(0.0f), n3 = (f32x2)(0.0f);
#pragma unroll
      for (int k = 0; k < 32; k += 4) {
        n0 = g2[k] * g2[k] + n0;
        n1 = g2[k + 1] * g2[k + 1] + n1;
        n2 = g2[k + 2] * g2[k + 2] + n2;
        n3 = g2[k + 3] * g2[k + 3] + n3;
      }
      const f32x2 nt = (n0 + n1) + (n2 + n3);
      s2 = nt.x + nt.y;
    }
    const float sigma = sqrtf(s2);
    const float coef = (sigma > 1e-30f) ? rsqrtf(sigma) : 0.0f;
#pragma unroll
    for (int k = 0; k < 32; ++k) {
      Al[(2 * k) * 68 + lane] = g2[k].x * coef;
      Al[(2 * k + 1) * 68 + lane] = g2[k].y * coef;
    }

  } else if (wave == 1) {
    // ========== consumer: V columns (replay, packed, ndone-aware) ==========
    f32x2 v2[32];
#pragma unroll
    for (int k = 0; k < 32; ++k)
      v2[k] = (f32x2){(2 * k == lane) ? 1.0f : 0.0f, (2 * k + 1 == lane) ? 1.0f : 0.0f};

    int m = 1;
    int addr = lane4 ^ (m << 2);
    int seen = 0;
    int nd = NR;
#pragma unroll 1
    for (int rg = 0; rg < NR; ++rg) {
      if (seen < rg + 1) {
        for (;;) {
          seen = __hip_atomic_load(&pflag_s, __ATOMIC_ACQUIRE, __HIP_MEMORY_SCOPE_WORKGROUP);
          if (seen >= rg + 1) break;
          __builtin_amdgcn_s_sleep(1);
        }
      }
      if (seen >= NR)
        nd = __hip_atomic_load(&ndone_s, __ATOMIC_ACQUIRE, __HIP_MEMORY_SCOPE_WORKGROUP);

      if (rg < nd) {
        const float2 cs = ring[rg & 63][lane];
        const float c = cs.x, ns = -cs.y;
        const f32x2 c2 = {c, c}, ns2 = {ns, ns};
#pragma unroll
        for (int k = 0; k < 32; ++k) {
          f32x2 e;
          e.x = bperm(addr, v2[k].x);
          e.y = bperm(addr, v2[k].y);
          v2[k] = ns2 * e + c2 * v2[k];
        }
      }
      m = (m == 63) ? 1 : m + 1;
      addr = lane4 ^ (m << 2);

      if ((rg & 15) == 15 && lane == 0)
        __hip_atomic_store(&cflag_s, rg + 1, __ATOMIC_RELEASE, __HIP_MEMORY_SCOPE_WORKGROUP);
    }
#pragma unroll
    for (int k = 0; k < 32; ++k) {
      Vl[(2 * k) * 68 + lane] = v2[k].x;
      Vl[(2 * k + 1) * 68 + lane] = v2[k].y;
    }
  }
  // waves 2,3 park here
  __syncthreads();

  // ---- R = W * V^T; each wave computes 16 columns for all 64 rows ----
  float wr[64];
#pragma unroll
  for (int jb = 0; jb < 16; ++jb) {
    const float4 v4 = *reinterpret_cast<const float4*>(&Al[lane * 68 + jb * 4]);
    wr[4 * jb] = v4.x; wr[4 * jb + 1] = v4.y; wr[4 * jb + 2] = v4.z; wr[4 * jb + 3] = v4.w;
  }
  __syncthreads();  // snapshots taken; Al rows free for R

  const int j0 = wave * 16;
  float rvals[16];
  float ssq = 0.0f;
#pragma unroll 4
  for (int jj = 0; jj < 16; ++jj) {
    const float4* vr = reinterpret_cast<const float4*>(&Vl[(j0 + jj) * 68]);
    float c0 = 0, c1 = 0, c2 = 0, c3 = 0;
#pragma unroll
    for (int kb = 0; kb < 16; ++kb) {
      const float4 vv = vr[kb];   // broadcast: conflict-free
      c0 = fmaf(wr[4 * kb], vv.x, c0);
      c1 = fmaf(wr[4 * kb + 1], vv.y, c1);
      c2 = fmaf(wr[4 * kb + 2], vv.z, c2);
      c3 = fmaf(wr[4 * kb + 3], vv.w, c3);
    }
    const float accv = (c0 + c1) + (c2 + c3);  // R[lane][j0+jj]
    rvals[jj] = accv;
    ssq = fmaf(accv, accv, ssq);
  }
#pragma unroll
  for (int jj = 0; jj < 4; ++jj)
    *reinterpret_cast<float4*>(&Al[lane * 68 + j0 + 4 * jj]) =
        make_float4(rvals[4 * jj], rvals[4 * jj + 1], rvals[4 * jj + 2], rvals[4 * jj + 3]);

  // ---- ||R||_F^2 reduction, normalize, coalesced store ----
#pragma unroll
  for (int off = 32; off; off >>= 1) ssq += __shfl_xor(ssq, off, 64);
  if (lane == 0) red[wave] = ssq;
  __syncthreads();
  const float rn = rsqrtf(fmaxf(red[0] + red[1] + red[2] + red[3], 1e-24f));

#pragma unroll
  for (int u = 0; u < 16; ++u) {
    const int e = t + 256 * u;
    out[(size_t)b * 4096 + e] = Al[(e >> 6) * 68 + (e & 63)] * rn;
  }
}

extern "C" void kernel_launch(void* const* d_in, const int* in_sizes, int n_in,
                              void* d_out, int out_size, void* d_ws, size_t ws_size,
                              hipStream_t stream) {
  const float* x = (const float*)d_in[0];
  float* out = (float*)d_out;
  float* part = (float*)d_ws;

  int G = 32;
  while (G > 1 && (size_t)16 * G * 4096 * 4 > ws_size) G >>= 1;

  pool_kernel<<<dim3(16 * G), dim3(256), 0, stream>>>(x, part, G);
  svd_kernel<<<dim3(16), dim3(256), 0, stream>>>(part, out, G);
}

// Round 17
// 230.096 us; speedup vs baseline: 1.4182x; 1.4182x over previous
//
#include <hip/hip_runtime.h>
#include <math.h>

#define NSWEEP 5
#define NR (NSWEEP * 63)

typedef __attribute__((ext_vector_type(2))) float f32x2;

// ---------------------------------------------------------------------------
// Kernel 1: partial max-pooled outer products. Grid = B*G blocks.
// ---------------------------------------------------------------------------
__global__ __launch_bounds__(256) void pool_kernel(const float* __restrict__ x,
                                                   float* __restrict__ part,
                                                   int G) {
  __shared__ float xs[4096];
  const int t = threadIdx.x;
  const int blk = blockIdx.x;
  const int b = blk / G, g = blk % G;
  const int npb = 4096 / G;
  const int ntile = npb >> 6;
  const int n0 = g * npb;
  const int i0 = (t >> 4) * 4;
  const int j0 = (t & 15) * 4;

  float mv[4][4];
#pragma unroll
  for (int a = 0; a < 4; ++a)
#pragma unroll
    for (int c = 0; c < 4; ++c) mv[a][c] = -INFINITY;

  const float4* src = reinterpret_cast<const float4*>(x + ((size_t)b * 4096 + n0) * 64);
  float4* xs4 = reinterpret_cast<float4*>(xs);

  for (int tile = 0; tile < ntile; ++tile) {
#pragma unroll
    for (int q = 0; q < 4; ++q) xs4[t + 256 * q] = src[(size_t)tile * 1024 + t + 256 * q];
    __syncthreads();
#pragma unroll 4
    for (int n = 0; n < 64; ++n) {
      const float4 vi = *reinterpret_cast<const float4*>(&xs[n * 64 + i0]);
      const float4 vj = *reinterpret_cast<const float4*>(&xs[n * 64 + j0]);
      const float fi[4] = {vi.x, vi.y, vi.z, vi.w};
      const float fj[4] = {vj.x, vj.y, vj.z, vj.w};
#pragma unroll
      for (int a = 0; a < 4; ++a)
#pragma unroll
        for (int c = 0; c < 4; ++c)
          mv[a][c] = fmaxf(mv[a][c], fi[a] * fj[c]);
    }
    __syncthreads();
  }

#pragma unroll
  for (int a = 0; a < 4; ++a)
#pragma unroll
    for (int c = 0; c < 4; ++c)
      xs[(i0 + a) * 64 + (j0 + c)] = mv[a][c];
  __syncthreads();

  float* dst = part + ((size_t)b * G + g) * 4096;
#pragma unroll
  for (int q = 0; q < 16; ++q) dst[t + 256 * q] = xs[t + 256 * q];
}

// ---------------------------------------------------------------------------
// Kernel 2: one-sided Jacobi, XOR schedule (pairs lane^m, m=1..63).
//   wave0 producer: packed f32x2, fused rotate+next-fetch, early bb prefetch.
//   wave1 consumer: V replay from LDS ring (R13-proven sync), packed.
//   waves 2,3 park; all 4 waves run the proven R = W*V^T epilogue.
// NSWEEP=5: absmax floored at f32 forward error since R10 (frozen across 4
// rounding-changing edits); sweep-6 |s| ~ 1e-5..1e-4 -> truncation ~1e-4.
// ---------------------------------------------------------------------------
__device__ __forceinline__ float bperm(int byteaddr, float v) {
  return __int_as_float(__builtin_amdgcn_ds_bpermute(byteaddr, __float_as_int(v)));
}

__global__ __launch_bounds__(256, 1) void svd_kernel(const float* __restrict__ part,
                                                     float* __restrict__ out, int G) {
  __shared__ __align__(16) float Al[64 * 68];   // pooled A -> W -> R
  __shared__ __align__(16) float Vl[64 * 68];   // final V
  __shared__ float2 ring[64][64];
  __shared__ float red[4];
  __shared__ int pflag_s, cflag_s;

  const int b = blockIdx.x;
  const int t = threadIdx.x;
  const int wave = t >> 6, lane = t & 63;
  const int lane4 = lane << 2;

  if (t == 0) { pflag_s = 0; cflag_s = 0; }

  // ---- prologue: fused max-reduce of partials into Al (all 256 threads) ----
  const float4* p4 = reinterpret_cast<const float4*>(part) + (size_t)b * G * 1024;
  float4 acc[4];
#pragma unroll
  for (int u = 0; u < 4; ++u) acc[u] = p4[t + 256 * u];
#pragma unroll 2
  for (int g = 1; g < G; ++g) {
#pragma unroll
    for (int u = 0; u < 4; ++u) {
      const float4 v = p4[(size_t)g * 1024 + t + 256 * u];
      acc[u].x = fmaxf(acc[u].x, v.x);
      acc[u].y = fmaxf(acc[u].y, v.y);
      acc[u].z = fmaxf(acc[u].z, v.z);
      acc[u].w = fmaxf(acc[u].w, v.w);
    }
  }
#pragma unroll
  for (int u = 0; u < 4; ++u) {
    const int idx = t + 256 * u;
    const int i = idx >> 4;
    const int j = (idx & 15) * 4;
    *reinterpret_cast<float4*>(&Al[i * 68 + j]) = acc[u];
  }
  __syncthreads();

  if (wave == 0) {
    // ========== producer: packed columns, early bb prefetch ==========
    f32x2 g2[32], ex2[32];
#pragma unroll
    for (int k = 0; k < 32; ++k)
      g2[k] = (f32x2){Al[(2 * k) * 68 + lane], Al[(2 * k + 1) * 68 + lane]};

    float a;
    {
      f32x2 n0 = (f32x2)(0.0f), n1 = (f32x2)(0.0f), n2 = (f32x2)(0.0f), n3 = (f32x2)(0.0f);
#pragma unroll
      for (int k = 0; k < 32; k += 4) {
        n0 = g2[k] * g2[k] + n0;
        n1 = g2[k + 1] * g2[k + 1] + n1;
        n2 = g2[k + 2] * g2[k + 2] + n2;
        n3 = g2[k + 3] * g2[k + 3] + n3;
      }
      const f32x2 nt = (n0 + n1) + (n2 + n3);
      a = nt.x + nt.y;
    }

    int m = 1;
    int addr = lane4 ^ (m << 2);
#pragma unroll
    for (int k = 0; k < 32; ++k) {
      ex2[k].x = bperm(addr, g2[k].x);
      ex2[k].y = bperm(addr, g2[k].y);
    }
    float bb = bperm(addr, a);

#pragma unroll 1
    for (int rg = 0; rg < NR; ++rg) {
      // dot product over cached partner column (8 packed chains)
      float d;
      {
        f32x2 d0 = (f32x2)(0.0f), d1 = (f32x2)(0.0f), d2 = (f32x2)(0.0f), d3 = (f32x2)(0.0f);
        f32x2 d4 = (f32x2)(0.0f), d5 = (f32x2)(0.0f), d6 = (f32x2)(0.0f), d7 = (f32x2)(0.0f);
#pragma unroll
        for (int k = 0; k < 32; k += 8) {
          d0 = g2[k] * ex2[k] + d0;
          d1 = g2[k + 1] * ex2[k + 1] + d1;
          d2 = g2[k + 2] * ex2[k + 2] + d2;
          d3 = g2[k + 3] * ex2[k + 3] + d3;
          d4 = g2[k + 4] * ex2[k + 4] + d4;
          d5 = g2[k + 5] * ex2[k + 5] + d5;
          d6 = g2[k + 6] * ex2[k + 6] + d6;
          d7 = g2[k + 7] * ex2[k + 7] + d7;
        }
        const f32x2 dt = ((d0 + d1) + (d2 + d3)) + ((d4 + d5) + (d6 + d7));
        d = dt.x + dt.y;
      }

      // angle: c identical on both pair lanes, s opposite sign
      const int partner = lane ^ m;
      const float u = (bb - a) * 0.5f;                  // exactly negated on partner
      const float sg = (u != 0.0f) ? copysignf(1.0f, u)
                                   : ((lane < partner) ? 1.0f : -1.0f);
      const float q = fmaf(u, u, d * d);
      float c, s;
      if (q > 0.0f) {
        const float rh = rsqrtf(q);                     // 1/h
        const float cc = fmaf(0.5f * fabsf(u), rh, 0.5f);  // c^2
        const float rc = rsqrtf(cc);
        c = cc * rc;
        s = d * sg * rh * 0.5f * rc;
      } else {
        c = 1.0f; s = 0.0f;
      }
      const float ns = -s;
      const float aupd = fmaf(c * c, a, fmaf(s * s, bb, -2.0f * (c * s) * d));

      ring[rg & 63][lane] = make_float2(c, s);
      if ((rg & 15) == 15) {
        if (lane == 0)
          __hip_atomic_store(&pflag_s, rg + 1, __ATOMIC_RELEASE, __HIP_MEMORY_SCOPE_WORKGROUP);
        int cd = __hip_atomic_load(&cflag_s, __ATOMIC_ACQUIRE, __HIP_MEMORY_SCOPE_WORKGROUP);
        while (rg + 1 - cd > 40) {
          __builtin_amdgcn_s_sleep(1);
          cd = __hip_atomic_load(&cflag_s, __ATOMIC_ACQUIRE, __HIP_MEMORY_SCOPE_WORKGROUP);
        }
      }

      const int mn = (m == 63) ? 1 : m + 1;
      const int addrn = lane4 ^ (mn << 2);

      // EARLY bb prefetch (overlaps the rotate burst)
      float bbn = bperm(addrn, aupd);

      // fused: packed rotate own column, immediately issue next exchange
      const f32x2 c2 = {c, c}, ns2 = {ns, ns};
#pragma unroll
      for (int k = 0; k < 32; ++k) {
        g2[k] = ns2 * ex2[k] + c2 * g2[k];
        ex2[k].x = bperm(addrn, g2[k].x);
        ex2[k].y = bperm(addrn, g2[k].y);
      }

      if (mn == 1) {  // sweep boundary: exact norm refresh + bb re-fetch
        f32x2 n0 = (f32x2)(0.0f), n1 = (f32x2)(0.0f), n2 = (f32x2)(0.0f), n3 = (f32x2)(0.0f);
#pragma unroll
        for (int k = 0; k < 32; k += 4) {
          n0 = g2[k] * g2[k] + n0;
          n1 = g2[k + 1] * g2[k + 1] + n1;
          n2 = g2[k + 2] * g2[k + 2] + n2;
          n3 = g2[k + 3] * g2[k + 3] + n3;
        }
        const f32x2 nt = (n0 + n1) + (n2 + n3);
        a = nt.x + nt.y;
        bbn = bperm(addrn, a);
      } else {
        a = aupd;
      }
      bb = bbn;
      m = mn;
    }
    if (lane == 0)
      __hip_atomic_store(&pflag_s, NR, __ATOMIC_RELEASE, __HIP_MEMORY_SCOPE_WORKGROUP);

    // exact sigma; W = G * diag(sigma^{-1/2}) into Al
    float s2;
    {
      f32x2 n0 = (f32x2)(0.0f), n1 = (f32x2)(0.0f), n2 = (f32x2)(0.0f), n3 = (f32x2)(0.0f);
#pragma unroll
      for (int k = 0; k < 32; k += 4) {
        n0 = g2[k] * g2[k] + n0;
        n1 = g2[k + 1] * g2[k + 1] + n1;
        n2 = g2[k + 2] * g2[k + 2] + n2;
        n3 = g2[k + 3] * g2[k + 3] + n3;
      }
      const f32x2 nt = (n0 + n1) + (n2 + n3);
      s2 = nt.x + nt.y;
    }
    const float sigma = sqrtf(s2);
    const float coef = (sigma > 1e-30f) ? rsqrtf(sigma) : 0.0f;
#pragma unroll
    for (int k = 0; k < 32; ++k) {
      Al[(2 * k) * 68 + lane] = g2[k].x * coef;
      Al[(2 * k + 1) * 68 + lane] = g2[k].y * coef;
    }

  } else if (wave == 1) {
    // ========== consumer: V columns (replay, packed) ==========
    f32x2 v2[32];
#pragma unroll
    for (int k = 0; k < 32; ++k)
      v2[k] = (f32x2){(2 * k == lane) ? 1.0f : 0.0f, (2 * k + 1 == lane) ? 1.0f : 0.0f};

    int m = 1;
    int addr = lane4 ^ (m << 2);
    int seen = 0;
#pragma unroll 1
    for (int rg = 0; rg < NR; ++rg) {
      if (seen < rg + 1) {
        for (;;) {
          seen = __hip_atomic_load(&pflag_s, __ATOMIC_ACQUIRE, __HIP_MEMORY_SCOPE_WORKGROUP);
          if (seen >= rg + 1) break;
          __builtin_amdgcn_s_sleep(1);
        }
      }
      const float2 cs = ring[rg & 63][lane];
      const float c = cs.x, ns = -cs.y;
      const f32x2 c2 = {c, c}, ns2 = {ns, ns};

#pragma unroll
      for (int k = 0; k < 32; ++k) {
        f32x2 e;
        e.x = bperm(addr, v2[k].x);
        e.y = bperm(addr, v2[k].y);
        v2[k] = ns2 * e + c2 * v2[k];
      }
      m = (m == 63) ? 1 : m + 1;
      addr = lane4 ^ (m << 2);

      if ((rg & 15) == 15 && lane == 0)
        __hip_atomic_store(&cflag_s, rg + 1, __ATOMIC_RELEASE, __HIP_MEMORY_SCOPE_WORKGROUP);
    }
#pragma unroll
    for (int k = 0; k < 32; ++k) {
      Vl[(2 * k) * 68 + lane] = v2[k].x;
      Vl[(2 * k + 1) * 68 + lane] = v2[k].y;
    }
  }
  // waves 2,3 park here
  __syncthreads();

  // ---- R = W * V^T; each wave computes 16 columns for all 64 rows ----
  float wr[64];
#pragma unroll
  for (int jb = 0; jb < 16; ++jb) {
    const float4 v4 = *reinterpret_cast<const float4*>(&Al[lane * 68 + jb * 4]);
    wr[4 * jb] = v4.x; wr[4 * jb + 1] = v4.y; wr[4 * jb + 2] = v4.z; wr[4 * jb + 3] = v4.w;
  }
  __syncthreads();  // snapshots taken; Al rows free for R

  const int j0 = wave * 16;
  float rvals[16];
  float ssq = 0.0f;
#pragma unroll 4
  for (int jj = 0; jj < 16; ++jj) {
    const float4* vr = reinterpret_cast<const float4*>(&Vl[(j0 + jj) * 68]);
    float c0 = 0, c1 = 0, c2 = 0, c3 = 0;
#pragma unroll
    for (int kb = 0; kb < 16; ++kb) {
      const float4 vv = vr[kb];   // broadcast: conflict-free
      c0 = fmaf(wr[4 * kb], vv.x, c0);
      c1 = fmaf(wr[4 * kb + 1], vv.y, c1);
      c2 = fmaf(wr[4 * kb + 2], vv.z, c2);
      c3 = fmaf(wr[4 * kb + 3], vv.w, c3);
    }
    const float accv = (c0 + c1) + (c2 + c3);  // R[lane][j0+jj]
    rvals[jj] = accv;
    ssq = fmaf(accv, accv, ssq);
  }
#pragma unroll
  for (int jj = 0; jj < 4; ++jj)
    *reinterpret_cast<float4*>(&Al[lane * 68 + j0 + 4 * jj]) =
        make_float4(rvals[4 * jj], rvals[4 * jj + 1], rvals[4 * jj + 2], rvals[4 * jj + 3]);

  // ---- ||R||_F^2 reduction, normalize, coalesced store ----
#pragma unroll
  for (int off = 32; off; off >>= 1) ssq += __shfl_xor(ssq, off, 64);
  if (lane == 0) red[wave] = ssq;
  __syncthreads();
  const float rn = rsqrtf(fmaxf(red[0] + red[1] + red[2] + red[3], 1e-24f));

#pragma unroll
  for (int u = 0; u < 16; ++u) {
    const int e = t + 256 * u;
    out[(size_t)b * 4096 + e] = Al[(e >> 6) * 68 + (e & 63)] * rn;
  }
}

extern "C" void kernel_launch(void* const* d_in, const int* in_sizes, int n_in,
                              void* d_out, int out_size, void* d_ws, size_t ws_size,
                              hipStream_t stream) {
  const float* x = (const float*)d_in[0];
  float* out = (float*)d_out;
  float* part = (float*)d_ws;

  int G = 32;
  while (G > 1 && (size_t)16 * G * 4096 * 4 > ws_size) G >>= 1;

  pool_kernel<<<dim3(16 * G), dim3(256), 0, stream>>>(x, part, G);
  svd_kernel<<<dim3(16), dim3(256), 0, stream>>>(part, out, G);
}